// Round 14
// baseline (711.622 us; speedup 1.0000x reference)
//
#include <hip/hip_runtime.h>

#define D_ 256
#define T_ 2048
#define K_ 1024
#define L_ 8
#define B_ 16
#define THETA 0.5f
#define ECT 20

typedef _Float16 f16x8 __attribute__((ext_vector_type(8)));
typedef float    f32x4 __attribute__((ext_vector_type(4)));

typedef const __attribute__((address_space(1))) unsigned int* gas1_t;
typedef __attribute__((address_space(3))) unsigned int*       las3_t;

__device__ __forceinline__ void gls16(const void* g, void* l) {
    __builtin_amdgcn_global_load_lds((gas1_t)g, (las3_t)l, 16, 0, 0);
}
__device__ __forceinline__ void gls4(const void* g, void* l) {
    __builtin_amdgcn_global_load_lds((gas1_t)g, (las3_t)l, 4, 0, 0);
}

__device__ __forceinline__ unsigned long long packkey(float sc, unsigned cand) {
    const unsigned fb = __float_as_uint(sc);
    const unsigned ob = fb ^ ((unsigned)((int)fb >> 31) | 0x80000000u);
    return (((unsigned long long)ob) << 32) | cand;
}
__device__ __forceinline__ float unpackf(unsigned long long key) {
    const unsigned ob = (unsigned)(key >> 32);
    const unsigned fb = (ob & 0x80000000u) ? (ob ^ 0x80000000u) : ~ob;
    return __uint_as_float(fb);
}
__device__ __forceinline__ unsigned short f2h_bits(float s) {
    union { _Float16 f; unsigned short u; } cv; cv.f = (_Float16)s; return cv.u;
}
__device__ __forceinline__ float h_bits2f(unsigned short u) {
    union { _Float16 f; unsigned short u; } cv; cv.u = u; return (float)cv.f;
}

// ---------------------------------------------------------------------------
// Prep 1 (frozen): ww[l*K + c] = ||codebook[l][c]||^2
// ---------------------------------------------------------------------------
__global__ __launch_bounds__(256, 4)
void rvq_ww_kernel(const float* __restrict__ cb, float* __restrict__ ww) {
    const int row  = blockIdx.x * 4 + (threadIdx.x >> 6);
    const int lane = threadIdx.x & 63;
    const float4 v = *reinterpret_cast<const float4*>(cb + (size_t)row * D_ + (lane << 2));
    float s = v.x * v.x + v.y * v.y + v.z * v.z + v.w * v.w;
    #pragma unroll
    for (int off = 1; off < 64; off <<= 1) s += __shfl_xor(s, off, 64);
    if (lane == 0) ww[row] = s;
}

// ---------------------------------------------------------------------------
// Prep 2 (frozen, R11): codebooks f32 -> f16 in 16KB-tile LDS-image order.
// Granule e: lane=e&63, sub=(e>>6)&15, ch=(e>>10)&31, l=e>>15;
// n=sub&1, kk=sub>>1; content = cb[l][ch*32+n*16+c4][kk*32+g*8 ..]
// ---------------------------------------------------------------------------
__global__ __launch_bounds__(256)
void rvq_cvtp_kernel(const float* __restrict__ cb, _Float16* __restrict__ cbp) {
    const int e    = blockIdx.x * 256 + threadIdx.x;
    const int lane = e & 63, sub = (e >> 6) & 15, ch = (e >> 10) & 31, l = e >> 15;
    const int n = sub & 1, kk = sub >> 1, g = lane >> 4, c4 = lane & 15;
    const float* src = cb + (size_t)(l * 1024 + ch * 32 + n * 16 + c4) * D_ + kk * 32 + g * 8;
    const float4 a = *reinterpret_cast<const float4*>(src);
    const float4 b = *reinterpret_cast<const float4*>(src + 4);
    f16x8 v;
    v[0] = (_Float16)a.x; v[1] = (_Float16)a.y; v[2] = (_Float16)a.z; v[3] = (_Float16)a.w;
    v[4] = (_Float16)b.x; v[5] = (_Float16)b.y; v[6] = (_Float16)b.z; v[7] = (_Float16)b.w;
    *reinterpret_cast<f16x8*>(cbp + (size_t)e * 8) = v;
}

// ---------------------------------------------------------------------------
// Main (R14): R13 structure verbatim (K-split x2, 2 blocks/CU, LDS atomicMin
// combine) with __launch_bounds__(512,2) — VGPR cap back to 128, no spill.
// Decision arithmetic frozen.
// ---------------------------------------------------------------------------
__global__ __launch_bounds__(512, 2)
void rvq_main_kernel(const float* __restrict__ x, const float* __restrict__ cbf,
                     const _Float16* __restrict__ cb16p, const float* __restrict__ ww,
                     float* __restrict__ out) {
    __shared__ __align__(16) _Float16 bstage[2][2][8192];   // [half][buf] 16 KB tiles
    __shared__ float               wwall[1024];
    __shared__ unsigned long long  fin64[64];
    __shared__ unsigned long long  ex64[64];
    __shared__ unsigned            elist[8][16][ECT];
    __shared__ int                 ecnt[8][16];

    const int tid  = threadIdx.x;
    const int lane = tid & 63;
    const int wv   = tid >> 6;          // 0..7
    const int half = wv >> 2;           // candidate half
    const int grp  = wv & 3;            // token group
    const int c4   = lane & 15;
    const int g    = lane >> 4;
    const int tg   = blockIdx.x * 64 + grp * 16 + c4;
    const int b    = tg >> 11;
    const int tl   = tg & (T_ - 1);
    const size_t xbase = ((size_t)b << 19) + tl;

    // stage my half's tile (l, c) -> bstage[half][c&1]  (4 gls16 per wave)
    auto stage_tile = [&](int l, int c) {
        const int gt = l * 32 + half * 16 + c;
        const _Float16* s = cb16p + ((size_t)gt * 1024 + grp * 256 + lane) * 8;
        char* d = (char*)&bstage[half][c & 1][0] + grp * 4096;
        #pragma unroll
        for (int i = 0; i < 4; ++i)
            gls16(s + i * 512, d + i * 1024);
    };

    stage_tile(0, 0);

    // residual f32 in regs: r_[kk*8+e] = r[token c4][d = kk*32 + g*8 + e]
    float r_[64];
    #pragma unroll
    for (int kk = 0; kk < 8; ++kk)
        #pragma unroll
        for (int e = 0; e < 8; ++e)
            r_[kk * 8 + e] = x[xbase + (size_t)(kk * 32 + g * 8 + e) * T_];

    #pragma unroll 1
    for (int l = 0; l < L_; ++l) {
        const float* __restrict__ cblf = cbf + (size_t)l * K_ * D_;

        // per-layer init + ww staging (bit-exact f32 copy)
        if (tid < 64) { fin64[tid] = ~0ull; ex64[tid] = ~0ull; }
        if (lane < 16) ecnt[wv][lane] = 0;
        #pragma unroll
        for (int i = 0; i < 2; ++i)
            gls4(ww + l * 1024 + wv * 128 + i * 64 + lane, &wwall[wv * 128 + i * 64]);

        // ---- rr (frozen bitwise tree) ----
        float rrv;
        {
            float Tk[8];
            #pragma unroll
            for (int kk = 0; kk < 8; ++kk) {
                float4 v;
                v.x = r_[kk * 8 + 0]; v.y = r_[kk * 8 + 1];
                v.z = r_[kk * 8 + 2]; v.w = r_[kk * 8 + 3];
                float s = v.x * v.x + v.y * v.y + v.z * v.z + v.w * v.w;
                float4 u;
                u.x = r_[kk * 8 + 4]; u.y = r_[kk * 8 + 5];
                u.z = r_[kk * 8 + 6]; u.w = r_[kk * 8 + 7];
                float s2 = u.x * u.x + u.y * u.y + u.z * u.z + u.w * u.w;
                const float p  = s + s2;
                const float po = __shfl_xor(p, 16, 64);
                const float q  = p + po;
                const float qo = __shfl_xor(q, 32, 64);
                Tk[kk] = q + qo;
            }
            const float u01 = Tk[0] + Tk[1], u23 = Tk[2] + Tk[3];
            const float u45 = Tk[4] + Tk[5], u67 = Tk[6] + Tk[7];
            rrv = (u01 + u23) + (u45 + u67);
        }

        // f16 A-fragments (frozen values)
        f16x8 fr[8];
        #pragma unroll
        for (int kk = 0; kk < 8; ++kk)
            #pragma unroll
            for (int e = 0; e < 8; ++e)
                fr[kk][e] = (_Float16)r_[kk * 8 + e];

        unsigned long long bkl[4];
        float bth[4];
        #pragma unroll
        for (int j = 0; j < 4; ++j) {
            bkl[j] = packkey(__builtin_inff(), 0u);
            bth[j] = __builtin_inff();
        }

        __syncthreads();   // tile 0 + wwall resident; init visible

        // ---- screen: 16 steps x 32 cands per half ----
        #pragma unroll 1
        for (int c = 0; c < 16; ++c) {
            const int s = l * 16 + c;
            if (s + 1 < 128) stage_tile((s + 1) >> 4, (s + 1) & 15);

            const _Float16* bufp = &bstage[half][c & 1][0];
            f32x4 acc0 = (f32x4){0.f, 0.f, 0.f, 0.f};
            f32x4 acc1 = (f32x4){0.f, 0.f, 0.f, 0.f};

            #pragma unroll
            for (int kk = 0; kk < 8; ++kk) {
                const f16x8 b0 = *reinterpret_cast<const f16x8*>(
                    bufp + ((kk * 2 + 0) * 64 + lane) * 8);
                const f16x8 b1 = *reinterpret_cast<const f16x8*>(
                    bufp + ((kk * 2 + 1) * 64 + lane) * 8);
                acc0 = __builtin_amdgcn_mfma_f32_16x16x32_f16(fr[kk], b0, acc0, 0, 0, 0);
                acc1 = __builtin_amdgcn_mfma_f32_16x16x32_f16(fr[kk], b1, acc1, 0, 0, 0);
            }

            const int cbase = half * 512 + c * 32;
            #pragma unroll
            for (int n2 = 0; n2 < 2; ++n2) {
                const f32x4 av = n2 ? acc1 : acc0;
                const unsigned cand = (unsigned)(cbase + n2 * 16 + c4);
                const float wwv = wwall[cand];
                #pragma unroll
                for (int j = 0; j < 4; ++j) {
                    const float sc = fmaf(-2.0f, av[j], wwv);   // frozen screen score
                    const unsigned long long key = packkey(sc, cand);
                    const int tj = g * 4 + j;
                    if (key < bkl[j]) {
                        const float old = unpackf(bkl[j]);
                        if (old <= sc + THETA) {
                            const int p = atomicAdd(&ecnt[wv][tj], 1);
                            if (p < ECT)
                                elist[wv][tj][p] =
                                    (((unsigned)(bkl[j] & 0xffffull)) << 16) | f2h_bits(old);
                        }
                        bkl[j] = key;
                        bth[j] = sc + THETA;
                    } else if (sc <= bth[j]) {
                        const int p = atomicAdd(&ecnt[wv][tj], 1);
                        if (p < ECT)
                            elist[wv][tj][p] = (cand << 16) | f2h_bits(sc);
                    }
                }
            }

            __syncthreads();   // drain DMA + tile handoff
        }

        // ---- wave reduce (frozen butterfly) + lane-best pushes + global min ----
        unsigned long long wk[4];
        #pragma unroll
        for (int j = 0; j < 4; ++j) {
            unsigned long long k0 = bkl[j];
            #pragma unroll
            for (int off = 1; off < 16; off <<= 1) {
                const unsigned long long k2 = __shfl_xor(k0, off, 64);
                if (k2 < k0) k0 = k2;
            }
            wk[j] = k0;
            if (bkl[j] != k0) {
                const float ls = unpackf(bkl[j]);
                if (ls <= unpackf(k0) + THETA) {
                    const int tj = g * 4 + j;
                    const int p = atomicAdd(&ecnt[wv][tj], 1);
                    if (p < ECT)
                        elist[wv][tj][p] =
                            (((unsigned)(bkl[j] & 0xffffull)) << 16) | f2h_bits(ls);
                }
            }
            if (c4 == 0) atomicMin(&fin64[grp * 16 + g * 4 + j], k0);
        }
        __syncthreads();

        // wave-min push if not the global winner (coverage invariant)
        if (c4 == 0) {
            #pragma unroll
            for (int j = 0; j < 4; ++j) {
                const unsigned long long fk = fin64[grp * 16 + g * 4 + j];
                if (wk[j] != fk && unpackf(wk[j]) <= unpackf(fk) + THETA) {
                    const int tj = g * 4 + j;
                    const int p = atomicAdd(&ecnt[wv][tj], 1);
                    if (p < ECT)
                        elist[wv][tj][p] =
                            (((unsigned)(wk[j] & 0xffffull)) << 16) | f2h_bits(unpackf(wk[j]));
                }
            }
        }

        // winner for my token (LDS read, no shuffles)
        const unsigned long long fkt = fin64[grp * 16 + c4];
        const unsigned wincand = (unsigned)(fkt & 0xffffffffull);
        const float    gminmy  = unpackf(fkt);

        // ---- exact winner: 4-lane relay (frozen; both halves identical) ----
        unsigned long long bestk;
        {
            const float* wp = cblf + (size_t)wincand * D_;
            float4 wA = *reinterpret_cast<const float4*>(wp + g * 8);
            float4 wB = *reinterpret_cast<const float4*>(wp + g * 8 + 4);
            float4 nA = *reinterpret_cast<const float4*>(wp + 32 + g * 8);
            float4 nB = *reinterpret_cast<const float4*>(wp + 32 + g * 8 + 4);
            float a0 = 0.0f;
            #pragma unroll
            for (int s = 0; s < 32; ++s) {
                const int kk = s >> 2;
                if ((s & 3) == g) {
                    a0 = fmaf(wA.x, r_[kk * 8 + 0], a0);
                    a0 = fmaf(wA.y, r_[kk * 8 + 1], a0);
                    a0 = fmaf(wA.z, r_[kk * 8 + 2], a0);
                    a0 = fmaf(wA.w, r_[kk * 8 + 3], a0);
                    a0 = fmaf(wB.x, r_[kk * 8 + 4], a0);
                    a0 = fmaf(wB.y, r_[kk * 8 + 5], a0);
                    a0 = fmaf(wB.z, r_[kk * 8 + 6], a0);
                    a0 = fmaf(wB.w, r_[kk * 8 + 7], a0);
                    wA = nA; wB = nB;
                    if (kk + 2 < 8) {
                        nA = *reinterpret_cast<const float4*>(wp + (kk + 2) * 32 + g * 8);
                        nB = *reinterpret_cast<const float4*>(wp + (kk + 2) * 32 + g * 8 + 4);
                    }
                }
                a0 = __shfl(a0, (lane + 48) & 63, 64);
            }
            a0 = __shfl(a0, c4, 64);
            const float scw = __fadd_rn(__fsub_rn(rrv, __fmul_rn(2.0f, a0)), wwall[wincand]);
            bestk = packkey(scw, wincand);
        }

        // ---- extras: per-token relay with gmin filter (frozen) ----
        {
            const int myn = min(ecnt[wv][c4], ECT);
            const float gth = gminmy + THETA + 0.5f;   // f16-rounding margin
            #pragma unroll 1
            for (int i = 0; i < myn; ++i) {
                const unsigned e  = elist[wv][c4][i];
                const unsigned ec = e >> 16;
                const float hsc = h_bits2f((unsigned short)(e & 0xffffu));
                if (ec == wincand || hsc > gth) continue;
                const float* ep = cblf + (size_t)ec * D_;
                float4 wA = *reinterpret_cast<const float4*>(ep + g * 8);
                float4 wB = *reinterpret_cast<const float4*>(ep + g * 8 + 4);
                float4 nA = *reinterpret_cast<const float4*>(ep + 32 + g * 8);
                float4 nB = *reinterpret_cast<const float4*>(ep + 32 + g * 8 + 4);
                float q = 0.0f;
                #pragma unroll
                for (int s = 0; s < 32; ++s) {
                    const int kk = s >> 2;
                    if ((s & 3) == g) {
                        q = fmaf(wA.x, r_[kk * 8 + 0], q);
                        q = fmaf(wA.y, r_[kk * 8 + 1], q);
                        q = fmaf(wA.z, r_[kk * 8 + 2], q);
                        q = fmaf(wA.w, r_[kk * 8 + 3], q);
                        q = fmaf(wB.x, r_[kk * 8 + 4], q);
                        q = fmaf(wB.y, r_[kk * 8 + 5], q);
                        q = fmaf(wB.z, r_[kk * 8 + 6], q);
                        q = fmaf(wB.w, r_[kk * 8 + 7], q);
                        wA = nA; wB = nB;
                        if (kk + 2 < 8) {
                            nA = *reinterpret_cast<const float4*>(ep + (kk + 2) * 32 + g * 8);
                            nB = *reinterpret_cast<const float4*>(ep + (kk + 2) * 32 + g * 8 + 4);
                        }
                    }
                    q = __shfl(q, (lane + 48) & 63, 64);
                }
                q = __shfl(q, c4, 64);
                const float sce = __fadd_rn(__fsub_rn(rrv, __fmul_rn(2.0f, q)), wwall[ec]);
                const unsigned long long k2 = packkey(sce, ec);
                if (k2 < bestk) bestk = k2;
            }
        }

        if (g == 0) atomicMin(&ex64[grp * 16 + c4], bestk);
        __syncthreads();

        const unsigned fc = (unsigned)(ex64[grp * 16 + c4] & 0xffffffffull);
        if (g == 0 && half == 0)
            out[(size_t)B_ * D_ * T_ + ((size_t)b * L_ + l) * T_ + tl] = (float)fc;

        // ---- residual update (frozen element-wise f32; both halves same) ----
        {
            const float* up = cblf + (size_t)fc * D_;
            #pragma unroll
            for (int kk = 0; kk < 8; ++kk) {
                const float4 ua = *reinterpret_cast<const float4*>(up + kk * 32 + g * 8);
                const float4 ub = *reinterpret_cast<const float4*>(up + kk * 32 + g * 8 + 4);
                r_[kk * 8 + 0] = __fsub_rn(r_[kk * 8 + 0], ua.x);
                r_[kk * 8 + 1] = __fsub_rn(r_[kk * 8 + 1], ua.y);
                r_[kk * 8 + 2] = __fsub_rn(r_[kk * 8 + 2], ua.z);
                r_[kk * 8 + 3] = __fsub_rn(r_[kk * 8 + 3], ua.w);
                r_[kk * 8 + 4] = __fsub_rn(r_[kk * 8 + 4], ub.x);
                r_[kk * 8 + 5] = __fsub_rn(r_[kk * 8 + 5], ub.y);
                r_[kk * 8 + 6] = __fsub_rn(r_[kk * 8 + 6], ub.z);
                r_[kk * 8 + 7] = __fsub_rn(r_[kk * 8 + 7], ub.w);
            }
        }
        __syncthreads();   // protect fin64/ex64/elist before next layer's init
    }

    // epilogue (frozen): quantized = x - r_final  (half 0 writes)
    if (half == 0) {
        #pragma unroll
        for (int kk = 0; kk < 8; ++kk)
            #pragma unroll
            for (int e = 0; e < 8; ++e) {
                const size_t gi = xbase + (size_t)(kk * 32 + g * 8 + e) * T_;
                out[gi] = __fsub_rn(x[gi], r_[kk * 8 + e]);
            }
    }
}

extern "C" void kernel_launch(void* const* d_in, const int* in_sizes, int n_in,
                              void* d_out, int out_size, void* d_ws, size_t ws_size,
                              hipStream_t stream) {
    const float* x  = (const float*)d_in[0];
    const float* cb = (const float*)d_in[1];
    float* out = (float*)d_out;
    float*    ww    = (float*)d_ws;                       // 32 KB
    _Float16* cb16p = (_Float16*)((char*)d_ws + 32768);   // 4 MB (tile-image)

    hipLaunchKernelGGL(rvq_ww_kernel,   dim3((L_ * K_) / 4), dim3(256), 0, stream, cb, ww);
    hipLaunchKernelGGL(rvq_cvtp_kernel, dim3(1024), dim3(256), 0, stream, cb, cb16p);
    hipLaunchKernelGGL(rvq_main_kernel, dim3((B_ * T_) / 64), dim3(512), 0, stream,
                       x, cb, cb16p, ww, out);
}

// Round 15
// 462.621 us; speedup vs baseline: 1.5382x; 1.5382x over previous
//
#include <hip/hip_runtime.h>

#define D_ 256
#define T_ 2048
#define K_ 1024
#define L_ 8
#define B_ 16
#define THETA 0.5f
#define ECT 40
#define NTILE 64   // L_ * 8 tiles of 128 candidates

typedef _Float16 f16x8 __attribute__((ext_vector_type(8)));
typedef float    f32x4 __attribute__((ext_vector_type(4)));

typedef const __attribute__((address_space(1))) unsigned int* gas1_t;
typedef __attribute__((address_space(3))) unsigned int*       las3_t;

__device__ __forceinline__ void gls16(const void* g, void* l) {
    __builtin_amdgcn_global_load_lds((gas1_t)g, (las3_t)l, 16, 0, 0);
}
__device__ __forceinline__ void gls4(const void* g, void* l) {
    __builtin_amdgcn_global_load_lds((gas1_t)g, (las3_t)l, 4, 0, 0);
}

__device__ __forceinline__ unsigned long long packkey(float sc, unsigned cand) {
    const unsigned fb = __float_as_uint(sc);
    const unsigned ob = fb ^ ((unsigned)((int)fb >> 31) | 0x80000000u);
    return (((unsigned long long)ob) << 32) | cand;
}
__device__ __forceinline__ float unpackf(unsigned long long key) {
    const unsigned ob = (unsigned)(key >> 32);
    const unsigned fb = (ob & 0x80000000u) ? (ob ^ 0x80000000u) : ~ob;
    return __uint_as_float(fb);
}
__device__ __forceinline__ unsigned short f2h_bits(float s) {
    union { _Float16 f; unsigned short u; } cv; cv.f = (_Float16)s; return cv.u;
}
__device__ __forceinline__ float h_bits2f(unsigned short u) {
    union { _Float16 f; unsigned short u; } cv; cv.u = u; return (float)cv.f;
}

// ---------------------------------------------------------------------------
// Prep 1 (frozen): ww[l*K + c] = ||codebook[l][c]||^2
// ---------------------------------------------------------------------------
__global__ __launch_bounds__(256, 4)
void rvq_ww_kernel(const float* __restrict__ cb, float* __restrict__ ww) {
    const int row  = blockIdx.x * 4 + (threadIdx.x >> 6);
    const int lane = threadIdx.x & 63;
    const float4 v = *reinterpret_cast<const float4*>(cb + (size_t)row * D_ + (lane << 2));
    float s = v.x * v.x + v.y * v.y + v.z * v.z + v.w * v.w;
    #pragma unroll
    for (int off = 1; off < 64; off <<= 1) s += __shfl_xor(s, off, 64);
    if (lane == 0) ww[row] = s;
}

// ---------------------------------------------------------------------------
// Prep 2 (frozen, R12): codebooks f32 -> f16 in 64KB-tile LDS-image order.
// Granule e (16B): gt=e>>12 (tile = l*8+ch), q=e&4095, lane=q&63, nk=q>>6,
// n=nk&7, kk=nk>>3, c4=lane&15, g=lane>>4;
// content = cb[l][ch*128 + n*16 + c4][kk*32 + g*8 .. +8]
// ---------------------------------------------------------------------------
__global__ __launch_bounds__(256)
void rvq_cvtp_kernel(const float* __restrict__ cb, _Float16* __restrict__ cbp) {
    const int e    = blockIdx.x * 256 + threadIdx.x;
    const int gt   = e >> 12, q = e & 4095;
    const int lane = q & 63, nk = q >> 6;
    const int n = nk & 7, kk = nk >> 3, c4 = lane & 15, g = lane >> 4;
    const int l = gt >> 3, ch = gt & 7;
    const float* src = cb + (size_t)(l * 1024 + ch * 128 + n * 16 + c4) * D_ + kk * 32 + g * 8;
    const float4 a = *reinterpret_cast<const float4*>(src);
    const float4 b = *reinterpret_cast<const float4*>(src + 4);
    f16x8 v;
    v[0] = (_Float16)a.x; v[1] = (_Float16)a.y; v[2] = (_Float16)a.z; v[3] = (_Float16)a.w;
    v[4] = (_Float16)b.x; v[5] = (_Float16)b.y; v[6] = (_Float16)b.z; v[7] = (_Float16)b.w;
    *reinterpret_cast<f16x8*>(cbp + (size_t)e * 8) = v;
}

// ---------------------------------------------------------------------------
// Main (R15): R12 structure (512 thr, 2x64KB dbuf tiles, 8 barriers/layer)
// with register-pressure relief: on-the-fly f16 A conversion, acc[2]
// pair-outer loop, float strict-< filter (provably identical selection).
// Decision arithmetic frozen.
// ---------------------------------------------------------------------------
__global__ __launch_bounds__(512, 2)
void rvq_main_kernel(const float* __restrict__ x, const float* __restrict__ cbf,
                     const _Float16* __restrict__ cb16p, const float* __restrict__ ww,
                     float* __restrict__ out) {
    __shared__ __align__(16) _Float16 bstage[2][32768];   // 2 x 64 KB tiles
    __shared__ float    wwlds[2][128];
    __shared__ unsigned elist[8][16][ECT];
    __shared__ int      ecnt[8][16];

    const int tid  = threadIdx.x;
    const int lane = tid & 63;
    const int wv   = tid >> 6;          // 0..7
    const int c4   = lane & 15;
    const int g    = lane >> 4;
    const int tg   = blockIdx.x * 128 + wv * 16 + c4;
    const int b    = tg >> 11;
    const int tl   = tg & (T_ - 1);
    const size_t xbase = ((size_t)b << 19) + tl;

    // stage global tile gt -> buffer gt&1 (8 gls16/wave; ww by waves 0,1)
    auto stage_tile = [&](int gt) {
        const _Float16* s = cb16p + ((size_t)gt * 4096 + wv * 512 + lane) * 8;
        char* d = (char*)bstage[gt & 1] + wv * 8192;
        #pragma unroll
        for (int i = 0; i < 8; ++i)
            gls16(s + i * 512, d + i * 1024);
        if (wv < 2)
            gls4(ww + gt * 128 + wv * 64 + lane, &wwlds[gt & 1][wv * 64]);
    };

    stage_tile(0);

    // residual f32 in regs: r_[kk*8+e] = r[token c4][d = kk*32 + g*8 + e]
    float r_[64];
    #pragma unroll
    for (int kk = 0; kk < 8; ++kk)
        #pragma unroll
        for (int e = 0; e < 8; ++e)
            r_[kk * 8 + e] = x[xbase + (size_t)(kk * 32 + g * 8 + e) * T_];

    __syncthreads();   // tile 0 resident

    #pragma unroll 1
    for (int l = 0; l < L_; ++l) {
        const float* __restrict__ cblf = cbf + (size_t)l * K_ * D_;
        const float* __restrict__ wwl  = ww + l * K_;

        if (lane < 16) ecnt[wv][lane] = 0;

        // ---- rr (frozen bitwise tree) ----
        float rrv;
        {
            float Tk[8];
            #pragma unroll
            for (int kk = 0; kk < 8; ++kk) {
                float4 v;
                v.x = r_[kk * 8 + 0]; v.y = r_[kk * 8 + 1];
                v.z = r_[kk * 8 + 2]; v.w = r_[kk * 8 + 3];
                float s = v.x * v.x + v.y * v.y + v.z * v.z + v.w * v.w;
                float4 u;
                u.x = r_[kk * 8 + 4]; u.y = r_[kk * 8 + 5];
                u.z = r_[kk * 8 + 6]; u.w = r_[kk * 8 + 7];
                float s2 = u.x * u.x + u.y * u.y + u.z * u.z + u.w * u.w;
                const float p  = s + s2;
                const float po = __shfl_xor(p, 16, 64);
                const float q  = p + po;
                const float qo = __shfl_xor(q, 32, 64);
                Tk[kk] = q + qo;
            }
            const float u01 = Tk[0] + Tk[1], u23 = Tk[2] + Tk[3];
            const float u45 = Tk[4] + Tk[5], u67 = Tk[6] + Tk[7];
            rrv = (u01 + u23) + (u45 + u67);
        }

        // per-lane running best per j: float strict-< (== packkey-min, since
        // each lane's cands arrive in strictly increasing index order)
        float    bsc[4], bth[4];
        unsigned bcd[4];
        #pragma unroll
        for (int j = 0; j < 4; ++j) {
            bsc[j] = __builtin_inff(); bth[j] = __builtin_inff(); bcd[j] = 0u;
        }

        // ---- screen: 8 chunks x 128 cands; dbuf async DMA, 1 barrier/chunk ----
        #pragma unroll 1
        for (int c = 0; c < 8; ++c) {
            const int gt = l * 8 + c;
            if (gt + 1 < NTILE) stage_tile(gt + 1);

            const _Float16* bufp = bstage[gt & 1];
            const float*    wwp  = wwlds[gt & 1];
            const int base = c * 128;

            // candidate-pair outer, kk inner; on-the-fly A conversion
            #pragma unroll
            for (int np = 0; np < 4; ++np) {
                const int n0 = np * 2, n1 = np * 2 + 1;
                f32x4 a0 = (f32x4){0.f, 0.f, 0.f, 0.f};
                f32x4 a1 = (f32x4){0.f, 0.f, 0.f, 0.f};
                #pragma unroll
                for (int kk = 0; kk < 8; ++kk) {
                    f16x8 fx;
                    #pragma unroll
                    for (int e = 0; e < 8; ++e) fx[e] = (_Float16)r_[kk * 8 + e];
                    const f16x8 b0 = *reinterpret_cast<const f16x8*>(
                        bufp + ((kk * 8 + n0) * 64 + lane) * 8);
                    const f16x8 b1 = *reinterpret_cast<const f16x8*>(
                        bufp + ((kk * 8 + n1) * 64 + lane) * 8);
                    a0 = __builtin_amdgcn_mfma_f32_16x16x32_f16(fx, b0, a0, 0, 0, 0);
                    a1 = __builtin_amdgcn_mfma_f32_16x16x32_f16(fx, b1, a1, 0, 0, 0);
                }
                #pragma unroll
                for (int n2 = 0; n2 < 2; ++n2) {
                    const f32x4 av = n2 ? a1 : a0;
                    const unsigned cand = (unsigned)(base + (np * 2 + n2) * 16 + c4);
                    const float wwv = wwp[(np * 2 + n2) * 16 + c4];
                    #pragma unroll
                    for (int j = 0; j < 4; ++j) {
                        const float sc = fmaf(-2.0f, av[j], wwv);   // frozen score
                        const int tj = g * 4 + j;
                        if (sc < bsc[j]) {
                            if (bsc[j] <= sc + THETA) {               // displaced best
                                const int p = atomicAdd(&ecnt[wv][tj], 1);
                                if (p < ECT)
                                    elist[wv][tj][p] = (bcd[j] << 16) | f2h_bits(bsc[j]);
                            }
                            bsc[j] = sc; bcd[j] = cand; bth[j] = sc + THETA;
                        } else if (sc <= bth[j]) {
                            const int p = atomicAdd(&ecnt[wv][tj], 1);
                            if (p < ECT)
                                elist[wv][tj][p] = (cand << 16) | f2h_bits(sc);
                        }
                    }
                }
            }

            __syncthreads();   // drain DMA (implicit vmcnt 0) + tile handoff
        }

        // rebuild frozen u64 keys for the cross-lane reduce
        unsigned long long bkl[4];
        #pragma unroll
        for (int j = 0; j < 4; ++j) bkl[j] = packkey(bsc[j], bcd[j]);

        // ---- final cross-lane reduce + final-best pushes (frozen R12) ----
        unsigned long long gk[4];
        #pragma unroll
        for (int j = 0; j < 4; ++j) {
            unsigned long long k0 = bkl[j];
            #pragma unroll
            for (int off = 1; off < 16; off <<= 1) {
                const unsigned long long k2 = __shfl_xor(k0, off, 64);
                if (k2 < k0) k0 = k2;
            }
            gk[j] = k0;
            if (bkl[j] != k0) {
                const float ls = unpackf(bkl[j]);
                if (ls <= unpackf(k0) + THETA) {
                    const int tj = g * 4 + j;
                    const int p = atomicAdd(&ecnt[wv][tj], 1);
                    if (p < ECT)
                        elist[wv][tj][p] =
                            (((unsigned)(bkl[j] & 0xffffull)) << 16) | f2h_bits(ls);
                }
            }
        }

        // broadcast winner + gmin to owner lanes (frozen mux)
        unsigned bc0 = (unsigned)(gk[0] & 0xffffffffull);
        unsigned bc1 = (unsigned)(gk[1] & 0xffffffffull);
        unsigned bc2 = (unsigned)(gk[2] & 0xffffffffull);
        unsigned bc3 = (unsigned)(gk[3] & 0xffffffffull);
        float gm0 = unpackf(gk[0]), gm1 = unpackf(gk[1]);
        float gm2 = unpackf(gk[2]), gm3 = unpackf(gk[3]);
        const int srcl = (c4 >> 2) << 4;
        const unsigned w0 = __shfl(bc0, srcl, 64);
        const unsigned w1 = __shfl(bc1, srcl, 64);
        const unsigned w2 = __shfl(bc2, srcl, 64);
        const unsigned w3 = __shfl(bc3, srcl, 64);
        const float s0 = __shfl(gm0, srcl, 64);
        const float s1 = __shfl(gm1, srcl, 64);
        const float s2 = __shfl(gm2, srcl, 64);
        const float s3 = __shfl(gm3, srcl, 64);
        const unsigned wa = (c4 & 1) ? w1 : w0;
        const unsigned wb = (c4 & 1) ? w3 : w2;
        const unsigned wincand = (c4 & 2) ? wb : wa;
        const float sa = (c4 & 1) ? s1 : s0;
        const float sb = (c4 & 1) ? s3 : s2;
        const float gminmy = (c4 & 2) ? sb : sa;

        // ---- exact winner: 4-lane relay (frozen) ----
        unsigned long long bestk;
        {
            const float* wp = cblf + (size_t)wincand * D_;
            float4 wA = *reinterpret_cast<const float4*>(wp + g * 8);
            float4 wB = *reinterpret_cast<const float4*>(wp + g * 8 + 4);
            float4 nA = *reinterpret_cast<const float4*>(wp + 32 + g * 8);
            float4 nB = *reinterpret_cast<const float4*>(wp + 32 + g * 8 + 4);
            float a0 = 0.0f;
            #pragma unroll
            for (int s = 0; s < 32; ++s) {
                const int kk = s >> 2;
                if ((s & 3) == g) {
                    a0 = fmaf(wA.x, r_[kk * 8 + 0], a0);
                    a0 = fmaf(wA.y, r_[kk * 8 + 1], a0);
                    a0 = fmaf(wA.z, r_[kk * 8 + 2], a0);
                    a0 = fmaf(wA.w, r_[kk * 8 + 3], a0);
                    a0 = fmaf(wB.x, r_[kk * 8 + 4], a0);
                    a0 = fmaf(wB.y, r_[kk * 8 + 5], a0);
                    a0 = fmaf(wB.z, r_[kk * 8 + 6], a0);
                    a0 = fmaf(wB.w, r_[kk * 8 + 7], a0);
                    wA = nA; wB = nB;
                    if (kk + 2 < 8) {
                        nA = *reinterpret_cast<const float4*>(wp + (kk + 2) * 32 + g * 8);
                        nB = *reinterpret_cast<const float4*>(wp + (kk + 2) * 32 + g * 8 + 4);
                    }
                }
                a0 = __shfl(a0, (lane + 48) & 63, 64);
            }
            a0 = __shfl(a0, c4, 64);
            const float scw = __fadd_rn(__fsub_rn(rrv, __fmul_rn(2.0f, a0)), wwl[wincand]);
            bestk = packkey(scw, wincand);
        }

        // ---- extras: per-token relay with gmin filter (frozen) ----
        {
            const int myn = min(ecnt[wv][c4], ECT);
            const float gth = gminmy + THETA + 0.5f;   // f16-rounding margin
            #pragma unroll 1
            for (int i = 0; i < myn; ++i) {
                const unsigned e  = elist[wv][c4][i];
                const unsigned ec = e >> 16;
                const float hsc = h_bits2f((unsigned short)(e & 0xffffu));
                if (ec == wincand || hsc > gth) continue;
                const float* ep = cblf + (size_t)ec * D_;
                float4 wA = *reinterpret_cast<const float4*>(ep + g * 8);
                float4 wB = *reinterpret_cast<const float4*>(ep + g * 8 + 4);
                float4 nA = *reinterpret_cast<const float4*>(ep + 32 + g * 8);
                float4 nB = *reinterpret_cast<const float4*>(ep + 32 + g * 8 + 4);
                float q = 0.0f;
                #pragma unroll
                for (int s = 0; s < 32; ++s) {
                    const int kk = s >> 2;
                    if ((s & 3) == g) {
                        q = fmaf(wA.x, r_[kk * 8 + 0], q);
                        q = fmaf(wA.y, r_[kk * 8 + 1], q);
                        q = fmaf(wA.z, r_[kk * 8 + 2], q);
                        q = fmaf(wA.w, r_[kk * 8 + 3], q);
                        q = fmaf(wB.x, r_[kk * 8 + 4], q);
                        q = fmaf(wB.y, r_[kk * 8 + 5], q);
                        q = fmaf(wB.z, r_[kk * 8 + 6], q);
                        q = fmaf(wB.w, r_[kk * 8 + 7], q);
                        wA = nA; wB = nB;
                        if (kk + 2 < 8) {
                            nA = *reinterpret_cast<const float4*>(ep + (kk + 2) * 32 + g * 8);
                            nB = *reinterpret_cast<const float4*>(ep + (kk + 2) * 32 + g * 8 + 4);
                        }
                    }
                    q = __shfl(q, (lane + 48) & 63, 64);
                }
                q = __shfl(q, c4, 64);
                const float sce = __fadd_rn(__fsub_rn(rrv, __fmul_rn(2.0f, q)), wwl[ec]);
                const unsigned long long k2 = packkey(sce, ec);
                if (k2 < bestk) bestk = k2;
            }
        }

        const unsigned fc = (unsigned)(bestk & 0xffffffffull);
        if (g == 0)
            out[(size_t)B_ * D_ * T_ + ((size_t)b * L_ + l) * T_ + tl] = (float)fc;

        // ---- residual update (frozen element-wise f32) ----
        {
            const float* up = cblf + (size_t)fc * D_;
            #pragma unroll
            for (int kk = 0; kk < 8; ++kk) {
                const float4 ua = *reinterpret_cast<const float4*>(up + kk * 32 + g * 8);
                const float4 ub = *reinterpret_cast<const float4*>(up + kk * 32 + g * 8 + 4);
                r_[kk * 8 + 0] = __fsub_rn(r_[kk * 8 + 0], ua.x);
                r_[kk * 8 + 1] = __fsub_rn(r_[kk * 8 + 1], ua.y);
                r_[kk * 8 + 2] = __fsub_rn(r_[kk * 8 + 2], ua.z);
                r_[kk * 8 + 3] = __fsub_rn(r_[kk * 8 + 3], ua.w);
                r_[kk * 8 + 4] = __fsub_rn(r_[kk * 8 + 4], ub.x);
                r_[kk * 8 + 5] = __fsub_rn(r_[kk * 8 + 5], ub.y);
                r_[kk * 8 + 6] = __fsub_rn(r_[kk * 8 + 6], ub.z);
                r_[kk * 8 + 7] = __fsub_rn(r_[kk * 8 + 7], ub.w);
            }
        }
    }

    // epilogue (frozen): quantized = x - r_final
    #pragma unroll
    for (int kk = 0; kk < 8; ++kk)
        #pragma unroll
        for (int e = 0; e < 8; ++e) {
            const size_t gi = xbase + (size_t)(kk * 32 + g * 8 + e) * T_;
            out[gi] = __fsub_rn(x[gi], r_[kk * 8 + e]);
        }
}

extern "C" void kernel_launch(void* const* d_in, const int* in_sizes, int n_in,
                              void* d_out, int out_size, void* d_ws, size_t ws_size,
                              hipStream_t stream) {
    const float* x  = (const float*)d_in[0];
    const float* cb = (const float*)d_in[1];
    float* out = (float*)d_out;
    float*    ww    = (float*)d_ws;                       // 32 KB
    _Float16* cb16p = (_Float16*)((char*)d_ws + 32768);   // 4 MB (tile-image)

    hipLaunchKernelGGL(rvq_ww_kernel,   dim3((L_ * K_) / 4), dim3(256), 0, stream, cb, ww);
    hipLaunchKernelGGL(rvq_cvtp_kernel, dim3(1024), dim3(256), 0, stream, cb, cb16p);
    hipLaunchKernelGGL(rvq_main_kernel, dim3((B_ * T_) / 128), dim3(512), 0, stream,
                       x, cb, cb16p, ww, out);
}

// Round 16
// 453.590 us; speedup vs baseline: 1.5689x; 1.0199x over previous
//
#include <hip/hip_runtime.h>

#define D_ 256
#define T_ 2048
#define K_ 1024
#define L_ 8
#define B_ 16
#define THETA 0.5f
#define ECT 40

typedef _Float16 f16x8 __attribute__((ext_vector_type(8)));
typedef float    f32x4 __attribute__((ext_vector_type(4)));

typedef const __attribute__((address_space(1))) unsigned int* gas1_t;
typedef __attribute__((address_space(3))) unsigned int*       las3_t;

__device__ __forceinline__ void gls16(const void* g, void* l) {
    __builtin_amdgcn_global_load_lds((gas1_t)g, (las3_t)l, 16, 0, 0);
}
__device__ __forceinline__ void gls4(const void* g, void* l) {
    __builtin_amdgcn_global_load_lds((gas1_t)g, (las3_t)l, 4, 0, 0);
}

__device__ __forceinline__ unsigned long long packkey(float sc, unsigned cand) {
    const unsigned fb = __float_as_uint(sc);
    const unsigned ob = fb ^ ((unsigned)((int)fb >> 31) | 0x80000000u);
    return (((unsigned long long)ob) << 32) | cand;
}
__device__ __forceinline__ float unpackf(unsigned long long key) {
    const unsigned ob = (unsigned)(key >> 32);
    const unsigned fb = (ob & 0x80000000u) ? (ob ^ 0x80000000u) : ~ob;
    return __uint_as_float(fb);
}
__device__ __forceinline__ unsigned short f2h_bits(float s) {
    union { _Float16 f; unsigned short u; } cv; cv.f = (_Float16)s; return cv.u;
}
__device__ __forceinline__ float h_bits2f(unsigned short u) {
    union { _Float16 f; unsigned short u; } cv; cv.u = u; return (float)cv.f;
}

// ---------------------------------------------------------------------------
// Prep 1 (frozen): ww[l*K + c] = ||codebook[l][c]||^2
// ---------------------------------------------------------------------------
__global__ __launch_bounds__(256, 4)
void rvq_ww_kernel(const float* __restrict__ cb, float* __restrict__ ww) {
    const int row  = blockIdx.x * 4 + (threadIdx.x >> 6);
    const int lane = threadIdx.x & 63;
    const float4 v = *reinterpret_cast<const float4*>(cb + (size_t)row * D_ + (lane << 2));
    float s = v.x * v.x + v.y * v.y + v.z * v.z + v.w * v.w;
    #pragma unroll
    for (int off = 1; off < 64; off <<= 1) s += __shfl_xor(s, off, 64);
    if (lane == 0) ww[row] = s;
}

// ---------------------------------------------------------------------------
// Prep 2 (frozen, R12): codebooks f32 -> f16 in 64KB-tile LDS-image order.
// ---------------------------------------------------------------------------
__global__ __launch_bounds__(256)
void rvq_cvtp_kernel(const float* __restrict__ cb, _Float16* __restrict__ cbp) {
    const int e    = blockIdx.x * 256 + threadIdx.x;
    const int gt   = e >> 12, q = e & 4095;
    const int lane = q & 63, nk = q >> 6;
    const int n = nk & 7, kk = nk >> 3, c4 = lane & 15, g = lane >> 4;
    const int l = gt >> 3, ch = gt & 7;
    const float* src = cb + (size_t)(l * 1024 + ch * 128 + n * 16 + c4) * D_ + kk * 32 + g * 8;
    const float4 a = *reinterpret_cast<const float4*>(src);
    const float4 b = *reinterpret_cast<const float4*>(src + 4);
    f16x8 v;
    v[0] = (_Float16)a.x; v[1] = (_Float16)a.y; v[2] = (_Float16)a.z; v[3] = (_Float16)a.w;
    v[4] = (_Float16)b.x; v[5] = (_Float16)b.y; v[6] = (_Float16)b.z; v[7] = (_Float16)b.w;
    *reinterpret_cast<f16x8*>(cbp + (size_t)e * 8) = v;
}

// ---------------------------------------------------------------------------
// Main (R16): R15 screen verbatim; exact phase restructured to thread-
// parallel chains (winner + extras) reading an rf f32 mirror (aliases the
// staging pool). Decision arithmetic frozen (R1 chain order, packkey,
// push conditions, update, epilogue).
// ---------------------------------------------------------------------------
__global__ __launch_bounds__(512, 2)
void rvq_main_kernel(const float* __restrict__ x, const float* __restrict__ cbf,
                     const _Float16* __restrict__ cb16p, const float* __restrict__ ww,
                     float* __restrict__ out) {
    // pool: screen image = bstage(2x64KB)=131072 + wwlds(1KB); rf = 128x260x4 = 133120
    __shared__ __align__(16) char pool[133120];
    __shared__ unsigned           elist[8][16][ECT];
    __shared__ int                ecnt[8][16];
    __shared__ float              rrs[128];
    __shared__ unsigned long long fin64[128];
    __shared__ unsigned long long ex64[128];

    const int tid  = threadIdx.x;
    const int lane = tid & 63;
    const int wv   = tid >> 6;          // 0..7
    const int c4   = lane & 15;
    const int g    = lane >> 4;
    const int tg   = blockIdx.x * 128 + wv * 16 + c4;
    const int b    = tg >> 11;
    const int tl   = tg & (T_ - 1);
    const size_t xbase = ((size_t)b << 19) + tl;

    // stage global tile gt -> pool half gt&1 (8 gls16/wave; ww by waves 0,1)
    auto stage_tile = [&](int gt) {
        const _Float16* s = cb16p + ((size_t)gt * 4096 + wv * 512 + lane) * 8;
        char* d = pool + (gt & 1) * 65536 + wv * 8192;
        #pragma unroll
        for (int i = 0; i < 8; ++i)
            gls16(s + i * 512, d + i * 1024);
        if (wv < 2)
            gls4(ww + gt * 128 + wv * 64 + lane,
                 pool + 131072 + ((gt & 1) * 128 + wv * 64 + lane - lane) * 4);
    };
    // NOTE: gls4's LDS dst is wave-uniform base; HW adds lane*4.

    stage_tile(0);

    // residual f32 in regs: r_[kk*8+e] = r[token c4][d = kk*32 + g*8 + e]
    float r_[64];
    #pragma unroll
    for (int kk = 0; kk < 8; ++kk)
        #pragma unroll
        for (int e = 0; e < 8; ++e)
            r_[kk * 8 + e] = x[xbase + (size_t)(kk * 32 + g * 8 + e) * T_];

    __syncthreads();   // tile 0 resident

    #pragma unroll 1
    for (int l = 0; l < L_; ++l) {
        const float* __restrict__ cblf = cbf + (size_t)l * K_ * D_;
        const float* __restrict__ wwl  = ww + l * K_;

        if (lane < 16) ecnt[wv][lane] = 0;

        // ---- rr (frozen bitwise tree) ----
        float rrv;
        {
            float Tk[8];
            #pragma unroll
            for (int kk = 0; kk < 8; ++kk) {
                float4 v;
                v.x = r_[kk * 8 + 0]; v.y = r_[kk * 8 + 1];
                v.z = r_[kk * 8 + 2]; v.w = r_[kk * 8 + 3];
                float s = v.x * v.x + v.y * v.y + v.z * v.z + v.w * v.w;
                float4 u;
                u.x = r_[kk * 8 + 4]; u.y = r_[kk * 8 + 5];
                u.z = r_[kk * 8 + 6]; u.w = r_[kk * 8 + 7];
                float s2 = u.x * u.x + u.y * u.y + u.z * u.z + u.w * u.w;
                const float p  = s + s2;
                const float po = __shfl_xor(p, 16, 64);
                const float q  = p + po;
                const float qo = __shfl_xor(q, 32, 64);
                Tk[kk] = q + qo;
            }
            const float u01 = Tk[0] + Tk[1], u23 = Tk[2] + Tk[3];
            const float u45 = Tk[4] + Tk[5], u67 = Tk[6] + Tk[7];
            rrv = (u01 + u23) + (u45 + u67);
        }

        // per-lane running best per j (float strict-<; == packkey-min)
        float    bsc[4], bth[4];
        unsigned bcd[4];
        #pragma unroll
        for (int j = 0; j < 4; ++j) {
            bsc[j] = __builtin_inff(); bth[j] = __builtin_inff(); bcd[j] = 0u;
        }

        // ---- screen: 8 chunks x 128 cands (verbatim R15) ----
        #pragma unroll 1
        for (int c = 0; c < 8; ++c) {
            const int gt = l * 8 + c;
            if (c < 7) stage_tile(gt + 1);   // same-layer prefetch only

            const _Float16* bufp = (const _Float16*)(pool + (gt & 1) * 65536);
            const float*    wwp  = (const float*)(pool + 131072) + (gt & 1) * 128;
            const int base = c * 128;

            #pragma unroll
            for (int np = 0; np < 4; ++np) {
                const int n0 = np * 2, n1 = np * 2 + 1;
                f32x4 a0 = (f32x4){0.f, 0.f, 0.f, 0.f};
                f32x4 a1 = (f32x4){0.f, 0.f, 0.f, 0.f};
                #pragma unroll
                for (int kk = 0; kk < 8; ++kk) {
                    f16x8 fx;
                    #pragma unroll
                    for (int e = 0; e < 8; ++e) fx[e] = (_Float16)r_[kk * 8 + e];
                    const f16x8 b0 = *reinterpret_cast<const f16x8*>(
                        bufp + ((kk * 8 + n0) * 64 + lane) * 8);
                    const f16x8 b1 = *reinterpret_cast<const f16x8*>(
                        bufp + ((kk * 8 + n1) * 64 + lane) * 8);
                    a0 = __builtin_amdgcn_mfma_f32_16x16x32_f16(fx, b0, a0, 0, 0, 0);
                    a1 = __builtin_amdgcn_mfma_f32_16x16x32_f16(fx, b1, a1, 0, 0, 0);
                }
                #pragma unroll
                for (int n2 = 0; n2 < 2; ++n2) {
                    const f32x4 av = n2 ? a1 : a0;
                    const unsigned cand = (unsigned)(base + (np * 2 + n2) * 16 + c4);
                    const float wwv = wwp[(np * 2 + n2) * 16 + c4];
                    #pragma unroll
                    for (int j = 0; j < 4; ++j) {
                        const float sc = fmaf(-2.0f, av[j], wwv);   // frozen score
                        const int tj = g * 4 + j;
                        if (sc < bsc[j]) {
                            if (bsc[j] <= sc + THETA) {               // displaced best
                                const int p = atomicAdd(&ecnt[wv][tj], 1);
                                if (p < ECT)
                                    elist[wv][tj][p] = (bcd[j] << 16) | f2h_bits(bsc[j]);
                            }
                            bsc[j] = sc; bcd[j] = cand; bth[j] = sc + THETA;
                        } else if (sc <= bth[j]) {
                            const int p = atomicAdd(&ecnt[wv][tj], 1);
                            if (p < ECT)
                                elist[wv][tj][p] = (cand << 16) | f2h_bits(sc);
                        }
                    }
                }
            }

            __syncthreads();   // drain DMA + tile handoff
        }

        // ---- rf mirror write (bit-exact r_ copies), rrs, ex64 reset ----
        {
            float* rp = (float*)pool + (wv * 16 + c4) * 260 + g * 8;
            #pragma unroll
            for (int kk = 0; kk < 8; ++kk) {
                float4 v0; v0.x = r_[kk*8+0]; v0.y = r_[kk*8+1]; v0.z = r_[kk*8+2]; v0.w = r_[kk*8+3];
                float4 v1; v1.x = r_[kk*8+4]; v1.y = r_[kk*8+5]; v1.z = r_[kk*8+6]; v1.w = r_[kk*8+7];
                *reinterpret_cast<float4*>(rp + kk * 32)     = v0;
                *reinterpret_cast<float4*>(rp + kk * 32 + 4) = v1;
            }
        }
        if (g == 0) rrs[wv * 16 + c4] = rrv;
        if (tid < 128) ex64[tid] = ~0ull;

        // ---- cross-lane reduce + final-best pushes (frozen) + fin64 store ----
        {
            unsigned long long bkl[4];
            #pragma unroll
            for (int j = 0; j < 4; ++j) bkl[j] = packkey(bsc[j], bcd[j]);
            #pragma unroll
            for (int j = 0; j < 4; ++j) {
                unsigned long long k0 = bkl[j];
                #pragma unroll
                for (int off = 1; off < 16; off <<= 1) {
                    const unsigned long long k2 = __shfl_xor(k0, off, 64);
                    if (k2 < k0) k0 = k2;
                }
                if (bkl[j] != k0) {
                    const float ls = unpackf(bkl[j]);
                    if (ls <= unpackf(k0) + THETA) {
                        const int tj = g * 4 + j;
                        const int p = atomicAdd(&ecnt[wv][tj], 1);
                        if (p < ECT)
                            elist[wv][tj][p] =
                                (((unsigned)(bkl[j] & 0xffffull)) << 16) | f2h_bits(ls);
                    }
                }
                if (c4 == 0) fin64[wv * 16 + g * 4 + j] = k0;
            }
        }
        __syncthreads();   // rf, rrs, fin64, elist, ex64-reset visible

        // ---- thread-parallel exact chains: token = tid>>2, 4 threads/token ----
        {
            const int tok = tid >> 2, sub = tid & 3;
            const int twv = tok >> 4, ttj = tok & 15;
            const unsigned long long fk = fin64[tok];
            const unsigned wincand = (unsigned)(fk & 0xffffffffull);
            const float rrt = rrs[tok];
            const float gth = unpackf(fk) + THETA + 0.5f;   // f16-rounding margin
            const float* rp = (const float*)pool + tok * 260;
            unsigned long long bk = ~0ull;

            if (sub == 0) {   // winner chain (frozen R1 sequential order)
                const float* wp = cblf + (size_t)wincand * D_;
                float a0 = 0.0f;
                #pragma unroll 4
                for (int dc = 0; dc < D_; dc += 8) {
                    const float4 ra = *reinterpret_cast<const float4*>(rp + dc);
                    const float4 rb = *reinterpret_cast<const float4*>(rp + dc + 4);
                    const float4 wa4 = *reinterpret_cast<const float4*>(wp + dc);
                    const float4 wb4 = *reinterpret_cast<const float4*>(wp + dc + 4);
                    a0 = fmaf(wa4.x, ra.x, a0);
                    a0 = fmaf(wa4.y, ra.y, a0);
                    a0 = fmaf(wa4.z, ra.z, a0);
                    a0 = fmaf(wa4.w, ra.w, a0);
                    a0 = fmaf(wb4.x, rb.x, a0);
                    a0 = fmaf(wb4.y, rb.y, a0);
                    a0 = fmaf(wb4.z, rb.z, a0);
                    a0 = fmaf(wb4.w, rb.w, a0);
                }
                const float scw = __fadd_rn(__fsub_rn(rrt, __fmul_rn(2.0f, a0)), wwl[wincand]);
                bk = packkey(scw, wincand);
            }

            const int myn = min(ecnt[twv][ttj], ECT);
            #pragma unroll 1
            for (int i = sub; i < myn; i += 4) {
                const unsigned e  = elist[twv][ttj][i];
                const unsigned ec = e >> 16;
                const float hsc = h_bits2f((unsigned short)(e & 0xffffu));
                if (ec == wincand || hsc > gth) continue;
                const float* ep = cblf + (size_t)ec * D_;
                float q = 0.0f;
                #pragma unroll 4
                for (int dc = 0; dc < D_; dc += 8) {
                    const float4 ra = *reinterpret_cast<const float4*>(rp + dc);
                    const float4 rb = *reinterpret_cast<const float4*>(rp + dc + 4);
                    const float4 wa4 = *reinterpret_cast<const float4*>(ep + dc);
                    const float4 wb4 = *reinterpret_cast<const float4*>(ep + dc + 4);
                    q = fmaf(wa4.x, ra.x, q);
                    q = fmaf(wa4.y, ra.y, q);
                    q = fmaf(wa4.z, ra.z, q);
                    q = fmaf(wa4.w, ra.w, q);
                    q = fmaf(wb4.x, rb.x, q);
                    q = fmaf(wb4.y, rb.y, q);
                    q = fmaf(wb4.z, rb.z, q);
                    q = fmaf(wb4.w, rb.w, q);
                }
                const float sce = __fadd_rn(__fsub_rn(rrt, __fmul_rn(2.0f, q)), wwl[ec]);
                const unsigned long long k2 = packkey(sce, ec);
                if (k2 < bk) bk = k2;
            }

            if (bk != ~0ull) atomicMin(&ex64[tok], bk);
        }
        __syncthreads();   // chains done (rf reads complete)

        if (l + 1 < L_) stage_tile((l + 1) * 8);   // next layer tile 0 (overwrites rf region)

        const unsigned fc = (unsigned)(ex64[wv * 16 + c4] & 0xffffffffull);
        if (g == 0)
            out[(size_t)B_ * D_ * T_ + ((size_t)b * L_ + l) * T_ + tl] = (float)fc;

        // ---- residual update (frozen element-wise f32) ----
        {
            const float* up = cblf + (size_t)fc * D_;
            #pragma unroll
            for (int kk = 0; kk < 8; ++kk) {
                const float4 ua = *reinterpret_cast<const float4*>(up + kk * 32 + g * 8);
                const float4 ub = *reinterpret_cast<const float4*>(up + kk * 32 + g * 8 + 4);
                r_[kk * 8 + 0] = __fsub_rn(r_[kk * 8 + 0], ua.x);
                r_[kk * 8 + 1] = __fsub_rn(r_[kk * 8 + 1], ua.y);
                r_[kk * 8 + 2] = __fsub_rn(r_[kk * 8 + 2], ua.z);
                r_[kk * 8 + 3] = __fsub_rn(r_[kk * 8 + 3], ua.w);
                r_[kk * 8 + 4] = __fsub_rn(r_[kk * 8 + 4], ub.x);
                r_[kk * 8 + 5] = __fsub_rn(r_[kk * 8 + 5], ub.y);
                r_[kk * 8 + 6] = __fsub_rn(r_[kk * 8 + 6], ub.z);
                r_[kk * 8 + 7] = __fsub_rn(r_[kk * 8 + 7], ub.w);
            }
        }
        __syncthreads();   // staging drained + visible; pool handed back to screen
    }

    // epilogue (frozen): quantized = x - r_final
    #pragma unroll
    for (int kk = 0; kk < 8; ++kk)
        #pragma unroll
        for (int e = 0; e < 8; ++e) {
            const size_t gi = xbase + (size_t)(kk * 32 + g * 8 + e) * T_;
            out[gi] = __fsub_rn(x[gi], r_[kk * 8 + e]);
        }
}

extern "C" void kernel_launch(void* const* d_in, const int* in_sizes, int n_in,
                              void* d_out, int out_size, void* d_ws, size_t ws_size,
                              hipStream_t stream) {
    const float* x  = (const float*)d_in[0];
    const float* cb = (const float*)d_in[1];
    float* out = (float*)d_out;
    float*    ww    = (float*)d_ws;                       // 32 KB
    _Float16* cb16p = (_Float16*)((char*)d_ws + 32768);   // 4 MB (tile-image)

    hipLaunchKernelGGL(rvq_ww_kernel,   dim3((L_ * K_) / 4), dim3(256), 0, stream, cb, ww);
    hipLaunchKernelGGL(rvq_cvtp_kernel, dim3(1024), dim3(256), 0, stream, cb, cb16p);
    hipLaunchKernelGGL(rvq_main_kernel, dim3((B_ * T_) / 128), dim3(512), 0, stream,
                       x, cb, cb16p, ww, out);
}